// Round 7
// baseline (609.399 us; speedup 1.0000x reference)
//
#include <hip/hip_runtime.h>

typedef float f4 __attribute__((ext_vector_type(4)));

#define Gn 4
#define Bn 2
#define Tn 32
#define Cn 128
#define CG 32      // channels per head-group
#define Hn 64
#define Wn 64
#define HC 16
#define WC 16

#define QT 16      // q-tile per block (q split across 2 blocks)
#define APAD 20    // Ah row stride in floats

// block = (g, b, h, whalf, qtile); 256 threads; thread tile = 4q x 4c x 4w.
// r7: Xs LDS staging deleted. r6 showed it was wave-private redistribution only;
// direct per-thread f4 loads have the identical cache-line footprint (2x128B
// segments per instr), so x is prefetched into REGISTERS (1-deep rotate) and
// LDS holds Ah only (25.6 KB). No asm waits needed - compiler emits counted
// vmcnt before first xcur use while xnxt loads stay in flight.
// Taps: 4x ds_read_b32, q strided (qsl+4i): bank = 20j+qsl+4i mod 32 covers all
// 32 banks once -> conflict-free (measured r6: conflicts 7.34M -> 1.05M).
// launch_bounds(256,4): ~116 VGPRs needed; NEVER cap tighter (r3/r4: a 85-VGPR
// cap spilled acc -> 7x HBM write amplification, WRITE 928MB vs 131MB).
__global__ __launch_bounds__(256, 4)
void temporal_agg_kernel(const float* __restrict__ x,
                         const float* __restrict__ attn,
                         float* __restrict__ out) {
    const int bid   = blockIdx.x;
    // qt pair members differ by 8 in dispatch index -> same XCD under round-robin
    // mod-8 assignment; x's doubled reads hit that XCD's L2 (confirmed r5/r6:
    // FETCH stayed ~98MB with x read twice).
    const int qt    = (bid >> 3) & 1;
    const int pair  = ((bid >> 4) << 3) | (bid & 7);   // [0, 1024)
    const int whalf = pair & 1;
    const int h     = (pair >> 1) & 63;
    const int b     = (pair >> 7) & 1;
    const int g     = pair >> 8;

    const int tid = threadIdx.x;

    __shared__ float Ah[Tn][10][APAD];    // 25.6 KB

    // ---- thread mapping for phase 2 (needed now for x prefetch) ----
    const int qsl   = tid & 3;         // q = qsl + 4*qq (strided -> b32 taps)
    const int wl    = (tid >> 2) & 7;  // 8 * 4 = 32 fine w in this half
    const int cslot = tid >> 5;        // 8 slots * 4 c = 32 c
    const int wfine = whalf * 32 + wl * 4;
    const int off_hw = h * Wn + wfine;
    const int cbase = g * CG + cslot * 4;
    const float* xb = x + (size_t)b * (Tn * Cn * Hn * Wn)
                        + (size_t)cbase * (Hn * Wn) + off_hw;

    // issue k=0 x loads BEFORE phase 1: their latency hides under attn staging
    f4 xcur[4], xnxt[4];
    #pragma unroll
    for (int cc = 0; cc < 4; ++cc)
        xcur[cc] = *(const f4*)(xb + cc * (Hn * Wn));

    // half-pixel h interpolation: src = 0.25*h - 0.375
    const float chf = 0.25f * (float)h - 0.375f;
    const float h0f = floorf(chf);
    const float fh  = chf - h0f;
    int h0 = (int)h0f;
    int h1 = h0 + 1;
    h0 = min(max(h0, 0), HC - 1);
    h1 = min(max(h1, 0), HC - 1);

    // ---- phase 1: attn -> LDS, h-lerp, transpose to q-fast ----
    const int wcb = whalf * 8 - 1;  // coarse col of j=0 (may be -1 -> clamped dup)
    const float* abase = attn + (size_t)(g * Bn + b) * (Tn * Tn * HC * WC)
                              + (size_t)(qt * QT) * (Tn * HC * WC);
    #pragma unroll 8
    for (int i = 0; i < 32; ++i) {
        int idx = tid + 256 * i;      // [0, 8192)
        int wc = idx & 15;
        int k  = (idx >> 4) & 31;
        int q  = idx >> 9;            // [0, 16)
        const float* p = abase + (size_t)(q * Tn + k) * (HC * WC);
        float v0 = p[h0 * WC + wc];
        float v1 = p[h1 * WC + wc];
        float ah = v0 + fh * (v1 - v0);
        int j = wc - wcb;
        if (j >= 0 && j < 10) Ah[k][j][q] = ah;
        if (whalf == 0 && wc == 0)  Ah[k][0][q] = ah;  // clamp(-1) -> col 0
        if (whalf == 1 && wc == 15) Ah[k][9][q] = ah;  // clamp(16) -> col 15
    }
    __syncthreads();

    // ---- phase 2: per-pixel temporal matmul, register-rotated x prefetch ----
    f4 acc[4][4];
    #pragma unroll
    for (int qq = 0; qq < 4; ++qq)
        #pragma unroll
        for (int cc = 0; cc < 4; ++cc)
            acc[qq][cc] = (f4)0.0f;

    #pragma unroll 2
    for (int k = 0; k < Tn; ++k) {
        if (k + 1 < Tn) {
            const float* xn = xb + (size_t)(k + 1) * (Cn * Hn * Wn);
            #pragma unroll
            for (int cc = 0; cc < 4; ++cc)
                xnxt[cc] = *(const f4*)(xn + cc * (Hn * Wn));
        }

        float t0[4], t1[4], t2[4];
        #pragma unroll
        for (int i = 0; i < 4; ++i) {
            t0[i] = Ah[k][wl    ][qsl + 4 * i];
            t1[i] = Ah[k][wl + 1][qsl + 4 * i];
            t2[i] = Ah[k][wl + 2][qsl + 4 * i];
        }

        #pragma unroll
        for (int qq = 0; qq < 4; ++qq) {
            f4 a;
            a.x = 0.375f * t0[qq] + 0.625f * t1[qq];
            a.y = 0.125f * t0[qq] + 0.875f * t1[qq];
            a.z = 0.875f * t1[qq] + 0.125f * t2[qq];
            a.w = 0.625f * t1[qq] + 0.375f * t2[qq];
            #pragma unroll
            for (int cc = 0; cc < 4; ++cc)
                acc[qq][cc] += a * xcur[cc];
        }

        if (k + 1 < Tn) {
            #pragma unroll
            for (int cc = 0; cc < 4; ++cc)
                xcur[cc] = xnxt[cc];
        }
    }

    // ---- epilogue: plain stores (nt stores caused 7x write amp, r3) ----
    #pragma unroll
    for (int qq = 0; qq < 4; ++qq) {
        const int q = qt * QT + qsl + 4 * qq;
        float* ob = out + ((size_t)(b * Tn + q) * Cn + cbase) * (Hn * Wn) + off_hw;
        #pragma unroll
        for (int cc = 0; cc < 4; ++cc)
            *(f4*)(ob + cc * (Hn * Wn)) = acc[qq][cc];
    }
}

extern "C" void kernel_launch(void* const* d_in, const int* in_sizes, int n_in,
                              void* d_out, int out_size, void* d_ws, size_t ws_size,
                              hipStream_t stream) {
    const float* x    = (const float*)d_in[0];
    const float* attn = (const float*)d_in[1];
    float* out        = (float*)d_out;
    temporal_agg_kernel<<<dim3(Gn * Bn * Hn * 2 * 2), dim3(256), 0, stream>>>(x, attn, out);
}

// Round 8
// 340.666 us; speedup vs baseline: 1.7888x; 1.7888x over previous
//
#include <hip/hip_runtime.h>

typedef float f4 __attribute__((ext_vector_type(4)));

#define Gn 4
#define Bn 2
#define Tn 32
#define Cn 128
#define CG 32      // channels per head-group
#define Hn 64
#define Wn 64
#define HC 16
#define WC 16

#define QT 16      // q-tile per block (q split across 2 blocks)
#define APAD 20    // Ah row stride in floats

// block = (g, b, h, whalf, qtile); 256 threads; thread tile = 4q x 4c x 4w.
// x prefetched into REGISTERS (1-deep rotate), LDS holds Ah only (25.6 KB).
// No asm waits: compiler emits counted vmcnt before first xcur use while the
// xnxt loads stay in flight, and freely overlaps k/k+1 ds_reads (r6's in-loop
// lgkmcnt(0) drain serialized every k -> all pipes <36% busy).
// Taps: 4x ds_read_b32, q strided (qsl+4i): bank = 20j+qsl+4i mod 32 covers all
// 32 banks once -> conflict-free (measured r6: conflicts 7.34M -> 1.05M).
// launch_bounds(256,3): unified arch+AGPR budget 170. This variant needs ~150
// (acc 64 AGPR + xcur/xnxt 32 + ~50 arch). The (256,4) cap of 128 SPILLED:
// r7 WRITE 880MB vs 131MB ideal, dur 456us. Spill invariant: WRITE==131072KB.
__global__ __launch_bounds__(256, 3)
void temporal_agg_kernel(const float* __restrict__ x,
                         const float* __restrict__ attn,
                         float* __restrict__ out) {
    const int bid   = blockIdx.x;
    // qt pair members differ by 8 in dispatch index -> same XCD under round-robin
    // mod-8 assignment; x's doubled reads hit that XCD's L2 (confirmed r5/r6:
    // FETCH stayed ~98MB with x read twice).
    const int qt    = (bid >> 3) & 1;
    const int pair  = ((bid >> 4) << 3) | (bid & 7);   // [0, 1024)
    const int whalf = pair & 1;
    const int h     = (pair >> 1) & 63;
    const int b     = (pair >> 7) & 1;
    const int g     = pair >> 8;

    const int tid = threadIdx.x;

    __shared__ float Ah[Tn][10][APAD];    // 25.6 KB

    // ---- thread mapping for phase 2 (needed now for x prefetch) ----
    const int qsl   = tid & 3;         // q = qsl + 4*qq (strided -> b32 taps)
    const int wl    = (tid >> 2) & 7;  // 8 * 4 = 32 fine w in this half
    const int cslot = tid >> 5;        // 8 slots * 4 c = 32 c
    const int wfine = whalf * 32 + wl * 4;
    const int off_hw = h * Wn + wfine;
    const int cbase = g * CG + cslot * 4;
    const float* xb = x + (size_t)b * (Tn * Cn * Hn * Wn)
                        + (size_t)cbase * (Hn * Wn) + off_hw;

    // issue k=0 x loads BEFORE phase 1: their latency hides under attn staging
    f4 xcur[4], xnxt[4];
    #pragma unroll
    for (int cc = 0; cc < 4; ++cc)
        xcur[cc] = *(const f4*)(xb + cc * (Hn * Wn));

    // half-pixel h interpolation: src = 0.25*h - 0.375
    const float chf = 0.25f * (float)h - 0.375f;
    const float h0f = floorf(chf);
    const float fh  = chf - h0f;
    int h0 = (int)h0f;
    int h1 = h0 + 1;
    h0 = min(max(h0, 0), HC - 1);
    h1 = min(max(h1, 0), HC - 1);

    // ---- phase 1: attn -> LDS, h-lerp, transpose to q-fast ----
    const int wcb = whalf * 8 - 1;  // coarse col of j=0 (may be -1 -> clamped dup)
    const float* abase = attn + (size_t)(g * Bn + b) * (Tn * Tn * HC * WC)
                              + (size_t)(qt * QT) * (Tn * HC * WC);
    #pragma unroll 8
    for (int i = 0; i < 32; ++i) {
        int idx = tid + 256 * i;      // [0, 8192)
        int wc = idx & 15;
        int k  = (idx >> 4) & 31;
        int q  = idx >> 9;            // [0, 16)
        const float* p = abase + (size_t)(q * Tn + k) * (HC * WC);
        float v0 = p[h0 * WC + wc];
        float v1 = p[h1 * WC + wc];
        float ah = v0 + fh * (v1 - v0);
        int j = wc - wcb;
        if (j >= 0 && j < 10) Ah[k][j][q] = ah;
        if (whalf == 0 && wc == 0)  Ah[k][0][q] = ah;  // clamp(-1) -> col 0
        if (whalf == 1 && wc == 15) Ah[k][9][q] = ah;  // clamp(16) -> col 15
    }
    __syncthreads();

    // ---- phase 2: per-pixel temporal matmul, register-rotated x prefetch ----
    f4 acc[4][4];
    #pragma unroll
    for (int qq = 0; qq < 4; ++qq)
        #pragma unroll
        for (int cc = 0; cc < 4; ++cc)
            acc[qq][cc] = (f4)0.0f;

    #pragma unroll 2
    for (int k = 0; k < Tn; ++k) {
        if (k + 1 < Tn) {
            const float* xn = xb + (size_t)(k + 1) * (Cn * Hn * Wn);
            #pragma unroll
            for (int cc = 0; cc < 4; ++cc)
                xnxt[cc] = *(const f4*)(xn + cc * (Hn * Wn));
        }

        float t0[4], t1[4], t2[4];
        #pragma unroll
        for (int i = 0; i < 4; ++i) {
            t0[i] = Ah[k][wl    ][qsl + 4 * i];
            t1[i] = Ah[k][wl + 1][qsl + 4 * i];
            t2[i] = Ah[k][wl + 2][qsl + 4 * i];
        }

        #pragma unroll
        for (int qq = 0; qq < 4; ++qq) {
            f4 a;
            a.x = 0.375f * t0[qq] + 0.625f * t1[qq];
            a.y = 0.125f * t0[qq] + 0.875f * t1[qq];
            a.z = 0.875f * t1[qq] + 0.125f * t2[qq];
            a.w = 0.625f * t1[qq] + 0.375f * t2[qq];
            #pragma unroll
            for (int cc = 0; cc < 4; ++cc)
                acc[qq][cc] += a * xcur[cc];
        }

        if (k + 1 < Tn) {
            #pragma unroll
            for (int cc = 0; cc < 4; ++cc)
                xcur[cc] = xnxt[cc];
        }
    }

    // ---- epilogue: plain stores (nt stores caused 7x write amp, r3) ----
    #pragma unroll
    for (int qq = 0; qq < 4; ++qq) {
        const int q = qt * QT + qsl + 4 * qq;
        float* ob = out + ((size_t)(b * Tn + q) * Cn + cbase) * (Hn * Wn) + off_hw;
        #pragma unroll
        for (int cc = 0; cc < 4; ++cc)
            *(f4*)(ob + cc * (Hn * Wn)) = acc[qq][cc];
    }
}

extern "C" void kernel_launch(void* const* d_in, const int* in_sizes, int n_in,
                              void* d_out, int out_size, void* d_ws, size_t ws_size,
                              hipStream_t stream) {
    const float* x    = (const float*)d_in[0];
    const float* attn = (const float*)d_in[1];
    float* out        = (float*)d_out;
    temporal_agg_kernel<<<dim3(Gn * Bn * Hn * 2 * 2), dim3(256), 0, stream>>>(x, attn, out);
}

// Round 10
// 302.496 us; speedup vs baseline: 2.0146x; 1.1262x over previous
//
#include <hip/hip_runtime.h>

typedef float f4 __attribute__((ext_vector_type(4)));
typedef const __attribute__((address_space(1))) void gas_t;
typedef __attribute__((address_space(3))) void las_t;

#define Gn 4
#define Bn 2
#define Tn 32
#define Cn 128
#define CG 32      // channels per head-group
#define Hn 64
#define Wn 64
#define HC 16
#define WC 16

#define QT 16      // q-tile per block (q split across 2 blocks)
#define APAD 20    // Ah row stride in floats
#define NSLOT 4    // x-staging slots, STATIC indices (slot = k & 3)

// block = (g, b, h, whalf, qtile); 256 threads; thread tile = 4q x 4c x 4w.
// x staged global->LDS via global_load_lds, 4 k-slices deep, wave-private
// (wave w stages channels 8w..8w+7 = exactly what its lanes consume).
// r9 vs r6 (140us, best): SAME depth-4 pipeline, but NO lgkmcnt(0) drain and
// no ring index. Static slots (k&3) let the compiler see the read->write alias
// on each slot, so program order alone gives WAR safety (DMA write lands
// >=200cy after issue; the ds_read accessed LDS earlier). Only fence left:
// one counted vmcnt per body (3 steady; 3/2/1/0 in the tail - exact counts).
// Taps: 4x ds_read_b32, q strided: bank = 20j+qsl+4i mod 32, conflict-free.
// launch_bounds(256,3): unified arch+AGPR budget 170; (256,4)=128 SPILLED r7
// (WRITE 880MB vs 131MB). Spill invariant each round: WRITE==131072KB.
__global__ __launch_bounds__(256, 3)
void temporal_agg_kernel(const float* __restrict__ x,
                         const float* __restrict__ attn,
                         float* __restrict__ out) {
    const int bid   = blockIdx.x;
    // qt pair members differ by 8 in dispatch index -> same XCD; x's doubled
    // reads hit that XCD's L2/L3 (confirmed r5-r8: FETCH ~98MB, x read twice).
    const int qt    = (bid >> 3) & 1;
    const int pair  = ((bid >> 4) << 3) | (bid & 7);   // [0, 1024)
    const int whalf = pair & 1;
    const int h     = (pair >> 1) & 63;
    const int b     = (pair >> 7) & 1;
    const int g     = pair >> 8;

    const int tid  = threadIdx.x;
    const int lane = tid & 63;
    const int wid  = tid >> 6;

    __shared__ float Ah[Tn][10][APAD];    // 25.6 KB
    __shared__ float Xs[NSLOT][CG][32];   // 16.0 KB -> 41.6 total, 3 blocks/CU

    // ---- x prefetch prologue: fire first NSLOT k-slices before phase 1;
    // their latency hides under the attn staging. Wave w lane l writes
    // Xs[s][8w + l/8][(l&7)*4] (HW: wave-uniform base + lane*16).
    const int c_ld = 8 * wid + (lane >> 3);
    const float* xsrc = x + ((size_t)(b * Tn) * Cn + (g * CG + c_ld)) * (Hn * Wn)
                          + h * Wn + whalf * 32 + (lane & 7) * 4;

#define STAGE(k_, s_) \
    __builtin_amdgcn_global_load_lds((gas_t*)(xsrc + (size_t)(k_) * (Cn * Hn * Wn)), \
                                     (las_t*)&Xs[s_][8 * wid][0], 16, 0, 0)

    STAGE(0, 0); STAGE(1, 1); STAGE(2, 2); STAGE(3, 3);

    // half-pixel h interpolation: src = 0.25*h - 0.375
    const float chf = 0.25f * (float)h - 0.375f;
    const float h0f = floorf(chf);
    const float fh  = chf - h0f;
    int h0 = (int)h0f;
    int h1 = h0 + 1;
    h0 = min(max(h0, 0), HC - 1);
    h1 = min(max(h1, 0), HC - 1);

    // ---- phase 1: attn -> LDS, h-lerp, transpose to q-fast ----
    const int wcb = whalf * 8 - 1;  // coarse col of j=0 (may be -1 -> clamped dup)
    const float* abase = attn + (size_t)(g * Bn + b) * (Tn * Tn * HC * WC)
                              + (size_t)(qt * QT) * (Tn * HC * WC);
    #pragma unroll 8
    for (int i = 0; i < 32; ++i) {
        int idx = tid + 256 * i;      // [0, 8192)
        int wc = idx & 15;
        int k  = (idx >> 4) & 31;
        int q  = idx >> 9;            // [0, 16)
        const float* p = abase + (size_t)(q * Tn + k) * (HC * WC);
        float v0 = p[h0 * WC + wc];
        float v1 = p[h1 * WC + wc];
        float ah = v0 + fh * (v1 - v0);
        int j = wc - wcb;
        if (j >= 0 && j < 10) Ah[k][j][q] = ah;
        if (whalf == 0 && wc == 0)  Ah[k][0][q] = ah;  // clamp(-1) -> col 0
        if (whalf == 1 && wc == 15) Ah[k][9][q] = ah;  // clamp(16) -> col 15
    }
    __syncthreads();

    // ---- phase 2: per-pixel temporal matmul, 4-deep static-slot pipeline ----
    const int qsl   = tid & 3;         // q = qsl + 4*qq (strided -> b32 taps)
    const int wl    = (tid >> 2) & 7;  // 8 * 4 = 32 fine w in this half
    const int cslot = tid >> 5;        // 8 slots * 4 c = 32 c
    const int wfine = whalf * 32 + wl * 4;
    const int off_hw = h * Wn + wfine;
    const int cbase = g * CG + cslot * 4;

    f4 acc[4][4];
    #pragma unroll
    for (int qq = 0; qq < 4; ++qq)
        #pragma unroll
        for (int cc = 0; cc < 4; ++cc)
            acc[qq][cc] = (f4)0.0f;

    // One body: counted vmcnt (oldest stage landed) -> taps + Xs reads ->
    // STAGE next slice into the SAME slot (issued before FMAs for max
    // in-flight time; alias with this body's reads keeps compile order) -> FMAs.
#define BODY(k_, s_, vn_, do_stage_)                                      \
    {                                                                     \
        asm volatile("s_waitcnt vmcnt(" #vn_ ")" ::: "memory");           \
        float t0[4], t1[4], t2[4];                                        \
        _Pragma("unroll")                                                 \
        for (int i = 0; i < 4; ++i) {                                     \
            t0[i] = Ah[k_][wl    ][qsl + 4 * i];                          \
            t1[i] = Ah[k_][wl + 1][qsl + 4 * i];                          \
            t2[i] = Ah[k_][wl + 2][qsl + 4 * i];                          \
        }                                                                 \
        f4 xv[4];                                                         \
        _Pragma("unroll")                                                 \
        for (int cc = 0; cc < 4; ++cc)                                    \
            xv[cc] = *(const f4*)&Xs[s_][cslot * 4 + cc][wl * 4];         \
        if (do_stage_) STAGE((k_) + NSLOT, s_);                           \
        _Pragma("unroll")                                                 \
        for (int qq = 0; qq < 4; ++qq) {                                  \
            f4 a;                                                         \
            a.x = 0.375f * t0[qq] + 0.625f * t1[qq];                      \
            a.y = 0.125f * t0[qq] + 0.875f * t1[qq];                      \
            a.z = 0.875f * t1[qq] + 0.125f * t2[qq];                      \
            a.w = 0.625f * t1[qq] + 0.375f * t2[qq];                      \
            _Pragma("unroll")                                             \
            for (int cc = 0; cc < 4; ++cc)                                \
                acc[qq][cc] += a * xv[cc];                                \
        }                                                                 \
    }

    for (int kk = 0; kk < Tn - NSLOT; kk += NSLOT) {
        BODY(kk + 0, 0, 3, 1)
        BODY(kk + 1, 1, 3, 1)
        BODY(kk + 2, 2, 3, 1)
        BODY(kk + 3, 3, 3, 1)
    }
    // tail: no more stages; exact outstanding counts 3/2/1/0
    BODY(Tn - 4, 0, 3, 0)
    BODY(Tn - 3, 1, 2, 0)
    BODY(Tn - 2, 2, 1, 0)
    BODY(Tn - 1, 3, 0, 0)
#undef BODY
#undef STAGE

    // ---- epilogue: plain stores (nt stores caused 7x write amp, r3) ----
    #pragma unroll
    for (int qq = 0; qq < 4; ++qq) {
        const int q = qt * QT + qsl + 4 * qq;
        float* ob = out + ((size_t)(b * Tn + q) * Cn + cbase) * (Hn * Wn) + off_hw;
        #pragma unroll
        for (int cc = 0; cc < 4; ++cc)
            *(f4*)(ob + cc * (Hn * Wn)) = acc[qq][cc];
    }
}

extern "C" void kernel_launch(void* const* d_in, const int* in_sizes, int n_in,
                              void* d_out, int out_size, void* d_ws, size_t ws_size,
                              hipStream_t stream) {
    const float* x    = (const float*)d_in[0];
    const float* attn = (const float*)d_in[1];
    float* out        = (float*)d_out;
    temporal_agg_kernel<<<dim3(Gn * Bn * Hn * 2 * 2), dim3(256), 0, stream>>>(x, attn, out);
}